// Round 2
// baseline (739.440 us; speedup 1.0000x reference)
//
#include <hip/hip_runtime.h>
#include <hip/hip_bf16.h>

#define N_NODES 50000
#define N_EDGES 600000

__device__ __forceinline__ float wave_sum(float v) {
#pragma unroll
  for (int m = 32; m > 0; m >>= 1) v += __shfl_xor(v, m, 64);
  return v;
}
__device__ __forceinline__ float wave_max(float v) {
#pragma unroll
  for (int m = 32; m > 0; m >>= 1) v = fmaxf(v, __shfl_xor(v, m, 64));
  return v;
}
__device__ __forceinline__ float leaky(float e) { return e > 0.f ? e : 0.2f * e; }

// ---------------- edge dtype detect + convert ----------------
// If edge_index is int64 (little-endian, values < 2^31), every odd int32 word
// is a zero high-half. Sample 64 odd positions; all-zero => int64.
__global__ void k_detect(const int* __restrict__ e, int* __restrict__ flag) {
  int t = threadIdx.x;  // 64 threads
  int idx = 1 + 2 * t * 4096;  // odd positions spread over first 600000 ints
  int v = e[idx];
  unsigned long long nz = __ballot(v != 0);
  if (t == 0) *flag = (nz == 0ULL) ? 1 : 0;  // 1 = int64
}
__global__ void k_convert(const int* __restrict__ e, const int* __restrict__ flag,
                          int* __restrict__ src32, int* __restrict__ dst32) {
  int i = blockIdx.x * 256 + threadIdx.x;
  if (i >= N_EDGES) return;
  int f = *flag;
  if (f) {  // int64 layout: row0 int64 idx i -> int32 idx 2i; row1 -> 2(E+i)
    src32[i] = e[2 * i];
    dst32[i] = e[2 * (N_EDGES + i)];
  } else {
    src32[i] = e[i];
    dst32[i] = e[N_EDGES + i];
  }
}

// ---------------- CSR build ----------------
__global__ void k_zero(int* p, int n) {
  int i = blockIdx.x * 256 + threadIdx.x;
  if (i < n) p[i] = 0;
}
__global__ void k_count(const int* __restrict__ dst, int* __restrict__ deg) {
  int e = blockIdx.x * 256 + threadIdx.x;
  if (e < N_EDGES) atomicAdd(&deg[dst[e]], 1);
}
__global__ void k_block_sums(const int* __restrict__ deg, int* __restrict__ part) {
  __shared__ int sd[256];
  int i = blockIdx.x * 256 + threadIdx.x;
  sd[threadIdx.x] = (i < N_NODES) ? deg[i] : 0;
  __syncthreads();
  for (int o = 128; o > 0; o >>= 1) {
    if (threadIdx.x < o) sd[threadIdx.x] += sd[threadIdx.x + o];
    __syncthreads();
  }
  if (threadIdx.x == 0) part[blockIdx.x] = sd[0];
}
__global__ void k_scan_part(int* part, int nb) {  // single block of 256
  __shared__ int s[256];
  int t = threadIdx.x;
  int v = (t < nb) ? part[t] : 0;
  s[t] = v;
  __syncthreads();
  for (int o = 1; o < 256; o <<= 1) {
    int x = (t >= o) ? s[t - o] : 0;
    __syncthreads();
    s[t] += x;
    __syncthreads();
  }
  if (t < nb) part[t] = s[t] - v;  // exclusive
}
__global__ void k_scan_apply(const int* __restrict__ deg, const int* __restrict__ part,
                             int* __restrict__ roff, int* __restrict__ cursor,
                             float* __restrict__ dinv) {
  __shared__ int s[256];
  int t = threadIdx.x;
  int i = blockIdx.x * 256 + t;
  int v = (i < N_NODES) ? deg[i] : 0;
  s[t] = v;
  __syncthreads();
  for (int o = 1; o < 256; o <<= 1) {
    int x = (t >= o) ? s[t - o] : 0;
    __syncthreads();
    s[t] += x;
    __syncthreads();
  }
  int off = part[blockIdx.x] + s[t] - v;  // exclusive prefix
  if (i < N_NODES) {
    roff[i] = off;
    cursor[i] = off;
    dinv[i] = rsqrtf((float)v + 1.f);  // +1 self-loop
    if (i == N_NODES - 1) roff[N_NODES] = off + v;
  }
}
__global__ void k_fill(const int* __restrict__ src, const int* __restrict__ dst,
                       int* __restrict__ cursor, int* __restrict__ adj) {
  int e = blockIdx.x * 256 + threadIdx.x;
  if (e < N_EDGES) {
    int d = dst[e];
    int pos = atomicAdd(&cursor[d], 1);
    adj[pos] = src[e];
  }
}
// fold GCN bias + BN into per-column affine: y = s*x + t
__global__ void k_affine(const float* b, const float* gamma, const float* beta,
                         const float* mean, const float* var, float* scale, float* shift) {
  int c = threadIdx.x;  // 128
  float s = gamma[c] * rsqrtf(var[c] + 1e-5f);
  scale[c] = s;
  shift[c] = (b[c] - mean[c]) * s + beta[c];
}

// ---------------- GEMM: Y[n,C] = T(X[n,128]) @ W[128,C] ----------------
// T = identity (mode 0), relu (mode 1), relu(affine) (mode 2)
template <int C>
__global__ __launch_bounds__(C) void gemm_k(const float* __restrict__ X,
                                            const float* __restrict__ W,
                                            float* __restrict__ Y,
                                            const float* __restrict__ scale,
                                            const float* __restrict__ shift, int mode) {
  __shared__ float xs[128 * 36];  // transposed tile: xs[k*36 + r], 16B-aligned rows
  int tid = threadIdx.x;
  int row0 = blockIdx.x * 32;
  for (int idx = tid; idx < 32 * 128; idx += C) {
    int r = idx >> 7, k = idx & 127;
    int row = row0 + r;
    float v = 0.f;
    if (row < N_NODES) {
      v = X[(size_t)row * 128 + k];
      if (mode == 2) v = v * scale[k] + shift[k];
      if (mode >= 1) v = fmaxf(v, 0.f);
    }
    xs[k * 36 + r] = v;
  }
  __syncthreads();
  float acc[32];
#pragma unroll
  for (int r = 0; r < 32; ++r) acc[r] = 0.f;
  const float* Wc = W + tid;
#pragma unroll 4
  for (int k = 0; k < 128; ++k) {
    float w = Wc[k * C];
    const float4* xr = (const float4*)&xs[k * 36];
#pragma unroll
    for (int q = 0; q < 8; ++q) {
      float4 xv = xr[q];
      acc[q * 4 + 0] = fmaf(xv.x, w, acc[q * 4 + 0]);
      acc[q * 4 + 1] = fmaf(xv.y, w, acc[q * 4 + 1]);
      acc[q * 4 + 2] = fmaf(xv.z, w, acc[q * 4 + 2]);
      acc[q * 4 + 3] = fmaf(xv.w, w, acc[q * 4 + 3]);
    }
  }
  int rmax = min(32, N_NODES - row0);
  for (int r = 0; r < rmax; ++r) Y[(size_t)(row0 + r) * C + tid] = acc[r];
}

// ---------------- GCN aggregation (pull, wave per dst node) ----------------
__global__ __launch_bounds__(256) void gcn_pull(const float* __restrict__ H,
                                                const int* __restrict__ adj,
                                                const int* __restrict__ roff,
                                                const float* __restrict__ dinv,
                                                float* __restrict__ out) {
  int wid = (blockIdx.x * 256 + threadIdx.x) >> 6;
  int lane = threadIdx.x & 63;
  if (wid >= N_NODES) return;
  int i = wid;
  int off = roff[i], end = roff[i + 1];
  float di = dinv[i];
  float a0 = H[(size_t)i * 128 + lane] * di;  // self-loop (norm = di*di, applied at end)
  float a1 = H[(size_t)i * 128 + 64 + lane] * di;
  for (int j = off; j < end; ++j) {
    int s = __builtin_amdgcn_readfirstlane(adj[j]);
    float ds = dinv[s];
    a0 = fmaf(H[(size_t)s * 128 + lane], ds, a0);
    a1 = fmaf(H[(size_t)s * 128 + 64 + lane], ds, a1);
  }
  out[(size_t)i * 128 + lane] = a0 * di;
  out[(size_t)i * 128 + 64 + lane] = a1 * di;
}

// ---------------- GAT attention logits: al_s/al_d [N,2] ----------------
template <int HD>  // per-head channels: 128 or 64
__global__ __launch_bounds__(256) void gat_al(const float* __restrict__ H,
                                              const float* __restrict__ a_src,
                                              const float* __restrict__ a_dst,
                                              float* __restrict__ als, float* __restrict__ ald) {
  int wid = (blockIdx.x * 256 + threadIdx.x) >> 6;
  int lane = threadIdx.x & 63;
  if (wid >= N_NODES) return;
  int i = wid;
  float s0, s1, d0, d1;
  if (HD == 128) {
    float h00 = H[(size_t)i * 256 + lane], h01 = H[(size_t)i * 256 + 64 + lane];
    float h10 = H[(size_t)i * 256 + 128 + lane], h11 = H[(size_t)i * 256 + 192 + lane];
    s0 = h00 * a_src[lane] + h01 * a_src[64 + lane];
    s1 = h10 * a_src[128 + lane] + h11 * a_src[192 + lane];
    d0 = h00 * a_dst[lane] + h01 * a_dst[64 + lane];
    d1 = h10 * a_dst[128 + lane] + h11 * a_dst[192 + lane];
  } else {
    float h0 = H[(size_t)i * 128 + lane], h1 = H[(size_t)i * 128 + 64 + lane];
    s0 = h0 * a_src[lane];
    s1 = h1 * a_src[64 + lane];
    d0 = h0 * a_dst[lane];
    d1 = h1 * a_dst[64 + lane];
  }
  s0 = wave_sum(s0); s1 = wave_sum(s1); d0 = wave_sum(d0); d1 = wave_sum(d1);
  if (lane == 0) {
    als[2 * i] = s0; als[2 * i + 1] = s1;
    ald[2 * i] = d0; ald[2 * i + 1] = d1;
  }
}

// ---------------- GAT aggregation (denominator fused, pull) ----------------
// out[i,c] = 0.5*sum_e alpha0_e*H[s,c] + 0.5*sum_e alpha1_e*H[s,HD+c] + bias[c]
template <int HD>
__global__ __launch_bounds__(256) void gat_pull(const float* __restrict__ H,
                                                const int* __restrict__ adj,
                                                const int* __restrict__ roff,
                                                const float* __restrict__ als,
                                                const float* __restrict__ ald,
                                                const float* __restrict__ bias,
                                                float* __restrict__ out) {
  int wid = (blockIdx.x * 256 + threadIdx.x) >> 6;
  int lane = threadIdx.x & 63;
  if (wid >= N_NODES) return;
  int i = wid;
  int off = roff[i], end = roff[i + 1];
  float ad0 = ald[2 * i], ad1 = ald[2 * i + 1];
  // denominator (softmax shift skipped: |e| small, exp safe in fp32)
  float p0 = 0.f, p1 = 0.f;
  for (int j = off + lane; j < end; j += 64) {
    int s = adj[j];
    p0 += __expf(leaky(als[2 * s] + ad0));
    p1 += __expf(leaky(als[2 * s + 1] + ad1));
  }
  p0 = wave_sum(p0);
  p1 = wave_sum(p1);
  float es0 = __expf(leaky(als[2 * i] + ad0));  // self-loop term
  float es1 = __expf(leaky(als[2 * i + 1] + ad1));
  float r0 = 0.5f / (p0 + es0), r1 = 0.5f / (p1 + es1);  // 0.5 = head mean
  float w0 = es0 * r0, w1 = es1 * r1;
  float a0 = w0 * H[(size_t)i * 2 * HD + lane] + w1 * H[(size_t)i * 2 * HD + HD + lane];
  float a1 = 0.f;
  if (HD == 128)
    a1 = w0 * H[(size_t)i * 256 + 64 + lane] + w1 * H[(size_t)i * 256 + 192 + lane];
  for (int j = off; j < end; ++j) {
    int s = __builtin_amdgcn_readfirstlane(adj[j]);
    float q0 = __expf(leaky(als[2 * s] + ad0)) * r0;
    float q1 = __expf(leaky(als[2 * s + 1] + ad1)) * r1;
    a0 += q0 * H[(size_t)s * 2 * HD + lane] + q1 * H[(size_t)s * 2 * HD + HD + lane];
    if (HD == 128)
      a1 += q0 * H[(size_t)s * 256 + 64 + lane] + q1 * H[(size_t)s * 256 + 192 + lane];
  }
  out[(size_t)i * HD + lane] = a0 + bias[lane];
  if (HD == 128) out[(size_t)i * 128 + 64 + lane] = a1 + bias[64 + lane];
}

// ---------------- log_softmax over 64 cols, wave per node ----------------
__global__ __launch_bounds__(256) void log_softmax_k(const float* __restrict__ X,
                                                     float* __restrict__ out) {
  int wid = (blockIdx.x * 256 + threadIdx.x) >> 6;
  int lane = threadIdx.x & 63;
  if (wid >= N_NODES) return;
  float v = X[(size_t)wid * 64 + lane];
  float m = wave_max(v);
  float s = wave_sum(__expf(v - m));
  out[(size_t)wid * 64 + lane] = v - m - __logf(s);
}

extern "C" void kernel_launch(void* const* d_in, const int* in_sizes, int n_in, void* d_out,
                              int out_size, void* d_ws, size_t ws_size, hipStream_t stream) {
  const float* x      = (const float*)d_in[0];
  const int* eidx     = (const int*)d_in[1];
  const float* W_gcn1 = (const float*)d_in[2];
  const float* b_gcn1 = (const float*)d_in[3];
  const float* bn1_g  = (const float*)d_in[4];
  const float* bn1_b  = (const float*)d_in[5];
  const float* bn1_m  = (const float*)d_in[6];
  const float* bn1_v  = (const float*)d_in[7];
  const float* W_gat1 = (const float*)d_in[8];
  const float* a_src1 = (const float*)d_in[9];
  const float* a_dst1 = (const float*)d_in[10];
  const float* b_gat1 = (const float*)d_in[11];
  const float* W_gcn2 = (const float*)d_in[12];
  const float* b_gcn2 = (const float*)d_in[13];
  const float* bn2_g  = (const float*)d_in[14];
  const float* bn2_b  = (const float*)d_in[15];
  const float* bn2_m  = (const float*)d_in[16];
  const float* bn2_v  = (const float*)d_in[17];
  const float* W_gat2 = (const float*)d_in[18];
  const float* a_src2 = (const float*)d_in[19];
  const float* a_dst2 = (const float*)d_in[20];
  const float* b_gat2 = (const float*)d_in[21];

  char* ws = (char*)d_ws;
  size_t o = 0;
  auto take = [&](size_t bytes) {
    char* p = ws + o;
    o = (o + bytes + 255) & ~(size_t)255;
    return p;
  };
  int* flag    = (int*)take(4);
  int* srcs    = (int*)take((size_t)N_EDGES * 4);
  int* dstsb   = (int*)take((size_t)N_EDGES * 4);
  int* deg     = (int*)take((size_t)N_NODES * 4);
  int* roff    = (int*)take((size_t)(N_NODES + 1) * 4);
  int* cursor  = (int*)take((size_t)N_NODES * 4);
  int* adj     = (int*)take((size_t)N_EDGES * 4);
  float* dinv  = (float*)take((size_t)N_NODES * 4);
  float* als   = (float*)take((size_t)2 * N_NODES * 4);
  float* ald   = (float*)take((size_t)2 * N_NODES * 4);
  float* sc1   = (float*)take(128 * 4);
  float* sh1   = (float*)take(128 * 4);
  float* sc2   = (float*)take(128 * 4);
  float* sh2   = (float*)take(128 * 4);
  int* part    = (int*)take(256 * 4);
  float* bufA  = (float*)take((size_t)N_NODES * 128 * 4);
  float* bufB  = (float*)take((size_t)N_NODES * 128 * 4);
  float* bufC  = (float*)take((size_t)N_NODES * 256 * 4);
  (void)ws_size; (void)in_sizes; (void)n_in; (void)out_size;

  int eb = (N_EDGES + 255) / 256;  // 2344
  int nb = (N_NODES + 255) / 256;  // 196
  int wb = (N_NODES + 3) / 4;      // 12500 (wave per node, 4 waves/block)
  int gb = (N_NODES + 31) / 32;    // 1563

  // edge dtype handling + CSR build + degree norm
  k_detect<<<1, 64, 0, stream>>>(eidx, flag);
  k_convert<<<eb, 256, 0, stream>>>(eidx, flag, srcs, dstsb);
  k_zero<<<nb, 256, 0, stream>>>(deg, N_NODES);
  k_count<<<eb, 256, 0, stream>>>(dstsb, deg);
  k_block_sums<<<nb, 256, 0, stream>>>(deg, part);
  k_scan_part<<<1, 256, 0, stream>>>(part, nb);
  k_scan_apply<<<nb, 256, 0, stream>>>(deg, part, roff, cursor, dinv);
  k_fill<<<eb, 256, 0, stream>>>(srcs, dstsb, cursor, adj);
  k_affine<<<1, 128, 0, stream>>>(b_gcn1, bn1_g, bn1_b, bn1_m, bn1_v, sc1, sh1);
  k_affine<<<1, 128, 0, stream>>>(b_gcn2, bn2_g, bn2_b, bn2_m, bn2_v, sc2, sh2);

  // Layer pipeline
  gemm_k<128><<<gb, 128, 0, stream>>>(x, W_gcn1, bufA, nullptr, nullptr, 0);
  gcn_pull<<<wb, 256, 0, stream>>>(bufA, adj, roff, dinv, bufB);
  gemm_k<256><<<gb, 256, 0, stream>>>(bufB, W_gat1, bufC, sc1, sh1, 2);
  gat_al<128><<<wb, 256, 0, stream>>>(bufC, a_src1, a_dst1, als, ald);
  gat_pull<128><<<wb, 256, 0, stream>>>(bufC, adj, roff, als, ald, b_gat1, bufA);
  gemm_k<128><<<gb, 128, 0, stream>>>(bufA, W_gcn2, bufB, nullptr, nullptr, 1);
  gcn_pull<<<wb, 256, 0, stream>>>(bufB, adj, roff, dinv, bufA);
  gemm_k<128><<<gb, 128, 0, stream>>>(bufA, W_gat2, bufB, sc2, sh2, 2);
  gat_al<64><<<wb, 256, 0, stream>>>(bufB, a_src2, a_dst2, als, ald);
  gat_pull<64><<<wb, 256, 0, stream>>>(bufB, adj, roff, als, ald, b_gat2, bufA);
  log_softmax_k<<<wb, 256, 0, stream>>>(bufA, (float*)d_out);
}

// Round 3
// 588.316 us; speedup vs baseline: 1.2569x; 1.2569x over previous
//
#include <hip/hip_runtime.h>
#include <hip/hip_bf16.h>

#define N_NODES 50000
#define N_EDGES 600000

typedef short bf16x8 __attribute__((ext_vector_type(8)));
typedef float f32x4 __attribute__((ext_vector_type(4)));

__device__ __forceinline__ float wave_sum(float v) {
#pragma unroll
  for (int m = 32; m > 0; m >>= 1) v += __shfl_xor(v, m, 64);
  return v;
}
__device__ __forceinline__ float wave_max(float v) {
#pragma unroll
  for (int m = 32; m > 0; m >>= 1) v = fmaxf(v, __shfl_xor(v, m, 64));
  return v;
}
__device__ __forceinline__ float leaky(float e) { return e > 0.f ? e : 0.2f * e; }
__device__ __forceinline__ unsigned short f2b(float f) {
  __hip_bfloat16 h = __float2bfloat16(f);
  return *reinterpret_cast<unsigned short*>(&h);
}
__device__ __forceinline__ float blo(unsigned int u) { return __uint_as_float(u << 16); }
__device__ __forceinline__ float bhi(unsigned int u) { return __uint_as_float(u & 0xffff0000u); }

// ---------------- edge dtype detect + convert ----------------
__global__ void k_detect(const int* __restrict__ e, int* __restrict__ flag) {
  int t = threadIdx.x;                 // 64 threads
  int idx = 1 + 2 * t * 4096;          // odd int32 positions
  int v = e[idx];
  unsigned long long nz = __ballot(v != 0);
  if (t == 0) *flag = (nz == 0ULL) ? 1 : 0;  // 1 = int64
}
__global__ void k_convert(const int* __restrict__ e, const int* __restrict__ flag,
                          int* __restrict__ src32, int* __restrict__ dst32) {
  int i = blockIdx.x * 256 + threadIdx.x;
  if (i >= N_EDGES) return;
  int f = *flag;
  if (f) {
    src32[i] = e[2 * i];
    dst32[i] = e[2 * (N_EDGES + i)];
  } else {
    src32[i] = e[i];
    dst32[i] = e[N_EDGES + i];
  }
}

// ---------------- CSR build ----------------
__global__ void k_zero(int* p, int n) {
  int i = blockIdx.x * 256 + threadIdx.x;
  if (i < n) p[i] = 0;
}
__global__ void k_count(const int* __restrict__ dst, int* __restrict__ deg) {
  int e = blockIdx.x * 256 + threadIdx.x;
  if (e < N_EDGES) atomicAdd(&deg[dst[e]], 1);
}
__global__ void k_block_sums(const int* __restrict__ deg, int* __restrict__ part) {
  __shared__ int sd[256];
  int i = blockIdx.x * 256 + threadIdx.x;
  sd[threadIdx.x] = (i < N_NODES) ? deg[i] : 0;
  __syncthreads();
  for (int o = 128; o > 0; o >>= 1) {
    if (threadIdx.x < o) sd[threadIdx.x] += sd[threadIdx.x + o];
    __syncthreads();
  }
  if (threadIdx.x == 0) part[blockIdx.x] = sd[0];
}
__global__ void k_scan_part(int* part, int nb) {
  __shared__ int s[256];
  int t = threadIdx.x;
  int v = (t < nb) ? part[t] : 0;
  s[t] = v;
  __syncthreads();
  for (int o = 1; o < 256; o <<= 1) {
    int x = (t >= o) ? s[t - o] : 0;
    __syncthreads();
    s[t] += x;
    __syncthreads();
  }
  if (t < nb) part[t] = s[t] - v;
}
__global__ void k_scan_apply(const int* __restrict__ deg, const int* __restrict__ part,
                             int* __restrict__ roff, int* __restrict__ cursor,
                             float* __restrict__ dinv) {
  __shared__ int s[256];
  int t = threadIdx.x;
  int i = blockIdx.x * 256 + t;
  int v = (i < N_NODES) ? deg[i] : 0;
  s[t] = v;
  __syncthreads();
  for (int o = 1; o < 256; o <<= 1) {
    int x = (t >= o) ? s[t - o] : 0;
    __syncthreads();
    s[t] += x;
    __syncthreads();
  }
  int off = part[blockIdx.x] + s[t] - v;
  if (i < N_NODES) {
    roff[i] = off;
    cursor[i] = off;
    dinv[i] = rsqrtf((float)v + 1.f);
    if (i == N_NODES - 1) roff[N_NODES] = off + v;
  }
}
__global__ void k_fill(const int* __restrict__ src, const int* __restrict__ dst,
                       int* __restrict__ cursor, int* __restrict__ adj) {
  int e = blockIdx.x * 256 + threadIdx.x;
  if (e < N_EDGES) {
    int d = dst[e];
    int pos = atomicAdd(&cursor[d], 1);
    adj[pos] = src[e];
  }
}
__global__ void k_affine(const float* b, const float* gamma, const float* beta,
                         const float* mean, const float* var, float* scale, float* shift) {
  int c = threadIdx.x;
  float s = gamma[c] * rsqrtf(var[c] + 1e-5f);
  scale[c] = s;
  shift[c] = (b[c] - mean[c]) * s + beta[c];
}
// W[k][C] fp32 -> Wt[c][128] bf16
__global__ void k_wt(const float* __restrict__ W, unsigned short* __restrict__ Wt, int C,
                     int logC) {
  int i = blockIdx.x * 256 + threadIdx.x;
  if (i >= 128 * C) return;
  int k = i >> logC, c = i & (C - 1);
  Wt[c * 128 + k] = f2b(W[i]);
}

// ---------------- MFMA GEMM: Hb[n,C] = bf16( T(X[n,128]) @ W[128,C] ) ----------
// T: 0=identity, 1=relu, 2=relu(affine). 64 rows/block, wave = 16 rows x C cols.
template <int C>
__global__ __launch_bounds__(256) void gemm_mfma(const float* __restrict__ X,
                                                 const unsigned short* __restrict__ Wt,
                                                 unsigned short* __restrict__ Hb,
                                                 const float* __restrict__ scale,
                                                 const float* __restrict__ shift, int mode) {
  __shared__ __align__(16) short smem[(C == 256) ? 16384 : 8704];
  int tid = threadIdx.x;
  int row0 = blockIdx.x * 64;
  // stage X (fp32 -> transform -> bf16), row stride 136 shorts (pad 8)
  for (int i = tid; i < 2048; i += 256) {
    int r = i >> 5;
    int k4 = (i & 31) * 4;
    int row = row0 + r;
    float4 v = make_float4(0.f, 0.f, 0.f, 0.f);
    if (row < N_NODES) v = *(const float4*)(X + (size_t)row * 128 + k4);
    if (mode == 2) {
      v.x = v.x * scale[k4] + shift[k4];
      v.y = v.y * scale[k4 + 1] + shift[k4 + 1];
      v.z = v.z * scale[k4 + 2] + shift[k4 + 2];
      v.w = v.w * scale[k4 + 3] + shift[k4 + 3];
    }
    if (mode >= 1) {
      v.x = fmaxf(v.x, 0.f); v.y = fmaxf(v.y, 0.f);
      v.z = fmaxf(v.z, 0.f); v.w = fmaxf(v.w, 0.f);
    }
    uint2 p;
    p.x = (unsigned int)f2b(v.x) | ((unsigned int)f2b(v.y) << 16);
    p.y = (unsigned int)f2b(v.z) | ((unsigned int)f2b(v.w) << 16);
    *(uint2*)&smem[r * 136 + k4] = p;
  }
  __syncthreads();
  int wave = tid >> 6, lane = tid & 63;
  int m = lane & 15, quad = lane >> 4;
  int rl0 = wave * 16;
  bf16x8 a[4];
#pragma unroll
  for (int kk = 0; kk < 4; ++kk)
    a[kk] = *(const bf16x8*)&smem[(rl0 + m) * 136 + kk * 32 + quad * 8];
  f32x4 acc[C / 16];
#pragma unroll
  for (int ct = 0; ct < C / 16; ++ct) acc[ct] = (f32x4){0.f, 0.f, 0.f, 0.f};
#pragma unroll
  for (int ct = 0; ct < C / 16; ++ct) {
    const unsigned short* wp = Wt + (size_t)(ct * 16 + m) * 128 + quad * 8;
#pragma unroll
    for (int kk = 0; kk < 4; ++kk) {
      bf16x8 b = *(const bf16x8*)(wp + kk * 32);
      acc[ct] = __builtin_amdgcn_mfma_f32_16x16x32_bf16(a[kk], b, acc[ct], 0, 0, 0);
    }
  }
  __syncthreads();
  // acc -> LDS (bf16, [64][C]) for coalesced store
#pragma unroll
  for (int ct = 0; ct < C / 16; ++ct) {
#pragma unroll
    for (int reg = 0; reg < 4; ++reg) {
      int rl = rl0 + quad * 4 + reg;
      smem[rl * C + ct * 16 + m] = (short)f2b(acc[ct][reg]);
    }
  }
  __syncthreads();
  for (int i = tid; i < 8 * C; i += 256) {  // uint4 chunks of the 64xC tile
    int row = row0 + (i * 8) / C;
    if (row < N_NODES)
      *(uint4*)((char*)Hb + (size_t)row0 * C * 2 + (size_t)i * 16) =
          *(uint4*)((char*)smem + (size_t)i * 16);
  }
}

// ---------------- GCN aggregation (pull, wave per node, bf16 gathers) ---------
__global__ __launch_bounds__(256) void gcn_pull(const unsigned short* __restrict__ Hb,
                                                const int* __restrict__ adj,
                                                const int* __restrict__ roff,
                                                const float* __restrict__ dinv,
                                                float* __restrict__ out) {
  int wid = (blockIdx.x * 256 + threadIdx.x) >> 6;
  int lane = threadIdx.x & 63;
  if (wid >= N_NODES) return;
  int i = wid;
  int off = roff[i], end = roff[i + 1];
  float di = dinv[i];
  unsigned int u = *(const unsigned int*)(Hb + (size_t)i * 128 + lane * 2);
  float a0 = blo(u) * di, a1 = bhi(u) * di;  // self-loop
  for (int j = off; j < end; ++j) {
    int s = __builtin_amdgcn_readfirstlane(adj[j]);
    float ds = dinv[s];
    unsigned int v = *(const unsigned int*)(Hb + (size_t)s * 128 + lane * 2);
    a0 = fmaf(blo(v), ds, a0);
    a1 = fmaf(bhi(v), ds, a1);
  }
  *(float2*)(out + (size_t)i * 128 + lane * 2) = make_float2(a0 * di, a1 * di);
}

// ---------------- GAT attention logits ----------------
template <int HD>
__global__ __launch_bounds__(256) void gat_al(const unsigned short* __restrict__ Hb,
                                              const float* __restrict__ a_src,
                                              const float* __restrict__ a_dst,
                                              float* __restrict__ als, float* __restrict__ ald) {
  int wid = (blockIdx.x * 256 + threadIdx.x) >> 6;
  int lane = threadIdx.x & 63;
  if (wid >= N_NODES) return;
  int i = wid;
  float s, d;
  if (HD == 128) {
    uint2 u = *(const uint2*)(Hb + (size_t)i * 256 + lane * 4);
    int c = lane * 4;
    float h0 = blo(u.x), h1 = bhi(u.x), h2 = blo(u.y), h3 = bhi(u.y);
    s = h0 * a_src[c] + h1 * a_src[c + 1] + h2 * a_src[c + 2] + h3 * a_src[c + 3];
    d = h0 * a_dst[c] + h1 * a_dst[c + 1] + h2 * a_dst[c + 2] + h3 * a_dst[c + 3];
  } else {
    unsigned int u = *(const unsigned int*)(Hb + (size_t)i * 128 + lane * 2);
    int c = lane * 2;
    s = blo(u) * a_src[c] + bhi(u) * a_src[c + 1];
    d = blo(u) * a_dst[c] + bhi(u) * a_dst[c + 1];
  }
#pragma unroll
  for (int mm = 16; mm > 0; mm >>= 1) {  // reduce within each 32-lane half (per head)
    s += __shfl_xor(s, mm, 64);
    d += __shfl_xor(d, mm, 64);
  }
  float s1 = __shfl(s, 32, 64), d1 = __shfl(d, 32, 64);
  if (lane == 0) {
    als[2 * i] = s; als[2 * i + 1] = s1;
    ald[2 * i] = d; ald[2 * i + 1] = d1;
  }
}

// ---------------- GAT aggregation (denominator fused, bf16 gathers) -----------
// lanes 0..31 = head0 channels, 32..63 = head1; shfl_xor(32) merges heads.
template <int HD>
__global__ __launch_bounds__(256) void gat_pull(const unsigned short* __restrict__ Hb,
                                                const int* __restrict__ adj,
                                                const int* __restrict__ roff,
                                                const float* __restrict__ als,
                                                const float* __restrict__ ald,
                                                const float* __restrict__ bias,
                                                float* __restrict__ out) {
  int wid = (blockIdx.x * 256 + threadIdx.x) >> 6;
  int lane = threadIdx.x & 63;
  if (wid >= N_NODES) return;
  int i = wid;
  int off = roff[i], end = roff[i + 1];
  float ad0 = ald[2 * i], ad1 = ald[2 * i + 1];
  float p0 = 0.f, p1 = 0.f;
  for (int j = off + lane; j < end; j += 64) {
    const float2 av = *(const float2*)(als + 2 * adj[j]);
    p0 += __expf(leaky(av.x + ad0));
    p1 += __expf(leaky(av.y + ad1));
  }
  p0 = wave_sum(p0);
  p1 = wave_sum(p1);
  float es0 = __expf(leaky(als[2 * i] + ad0));
  float es1 = __expf(leaky(als[2 * i + 1] + ad1));
  float r0 = 0.5f / (p0 + es0), r1 = 0.5f / (p1 + es1);  // 0.5 = head mean
  int head = lane >> 5;
  float wself = head ? es1 * r1 : es0 * r0;
  if (HD == 128) {
    uint2 u = *(const uint2*)(Hb + (size_t)i * 256 + lane * 4);
    float acc0 = wself * blo(u.x), acc1 = wself * bhi(u.x);
    float acc2 = wself * blo(u.y), acc3 = wself * bhi(u.y);
    for (int j = off; j < end; ++j) {
      int s = __builtin_amdgcn_readfirstlane(adj[j]);
      float q0 = __expf(leaky(als[2 * s] + ad0)) * r0;
      float q1 = __expf(leaky(als[2 * s + 1] + ad1)) * r1;
      float q = head ? q1 : q0;
      uint2 v = *(const uint2*)(Hb + (size_t)s * 256 + lane * 4);
      acc0 = fmaf(q, blo(v.x), acc0);
      acc1 = fmaf(q, bhi(v.x), acc1);
      acc2 = fmaf(q, blo(v.y), acc2);
      acc3 = fmaf(q, bhi(v.y), acc3);
    }
    acc0 += __shfl_xor(acc0, 32, 64);
    acc1 += __shfl_xor(acc1, 32, 64);
    acc2 += __shfl_xor(acc2, 32, 64);
    acc3 += __shfl_xor(acc3, 32, 64);
    if (lane < 32) {
      int c = lane * 4;
      *(float4*)(out + (size_t)i * 128 + c) =
          make_float4(acc0 + bias[c], acc1 + bias[c + 1], acc2 + bias[c + 2], acc3 + bias[c + 3]);
    }
  } else {
    unsigned int u = *(const unsigned int*)(Hb + (size_t)i * 128 + lane * 2);
    float acc0 = wself * blo(u), acc1 = wself * bhi(u);
    for (int j = off; j < end; ++j) {
      int s = __builtin_amdgcn_readfirstlane(adj[j]);
      float q0 = __expf(leaky(als[2 * s] + ad0)) * r0;
      float q1 = __expf(leaky(als[2 * s + 1] + ad1)) * r1;
      float q = head ? q1 : q0;
      unsigned int v = *(const unsigned int*)(Hb + (size_t)s * 128 + lane * 2);
      acc0 = fmaf(q, blo(v), acc0);
      acc1 = fmaf(q, bhi(v), acc1);
    }
    acc0 += __shfl_xor(acc0, 32, 64);
    acc1 += __shfl_xor(acc1, 32, 64);
    if (lane < 32) {
      int c = lane * 2;
      *(float2*)(out + (size_t)i * 64 + c) = make_float2(acc0 + bias[c], acc1 + bias[c + 1]);
    }
  }
}

// ---------------- log_softmax over 64 cols ----------------
__global__ __launch_bounds__(256) void log_softmax_k(const float* __restrict__ X,
                                                     float* __restrict__ out) {
  int wid = (blockIdx.x * 256 + threadIdx.x) >> 6;
  int lane = threadIdx.x & 63;
  if (wid >= N_NODES) return;
  float v = X[(size_t)wid * 64 + lane];
  float m = wave_max(v);
  float s = wave_sum(__expf(v - m));
  out[(size_t)wid * 64 + lane] = v - m - __logf(s);
}

extern "C" void kernel_launch(void* const* d_in, const int* in_sizes, int n_in, void* d_out,
                              int out_size, void* d_ws, size_t ws_size, hipStream_t stream) {
  const float* x      = (const float*)d_in[0];
  const int* eidx     = (const int*)d_in[1];
  const float* W_gcn1 = (const float*)d_in[2];
  const float* b_gcn1 = (const float*)d_in[3];
  const float* bn1_g  = (const float*)d_in[4];
  const float* bn1_b  = (const float*)d_in[5];
  const float* bn1_m  = (const float*)d_in[6];
  const float* bn1_v  = (const float*)d_in[7];
  const float* W_gat1 = (const float*)d_in[8];
  const float* a_src1 = (const float*)d_in[9];
  const float* a_dst1 = (const float*)d_in[10];
  const float* b_gat1 = (const float*)d_in[11];
  const float* W_gcn2 = (const float*)d_in[12];
  const float* b_gcn2 = (const float*)d_in[13];
  const float* bn2_g  = (const float*)d_in[14];
  const float* bn2_b  = (const float*)d_in[15];
  const float* bn2_m  = (const float*)d_in[16];
  const float* bn2_v  = (const float*)d_in[17];
  const float* W_gat2 = (const float*)d_in[18];
  const float* a_src2 = (const float*)d_in[19];
  const float* a_dst2 = (const float*)d_in[20];
  const float* b_gat2 = (const float*)d_in[21];

  char* ws = (char*)d_ws;
  size_t o = 0;
  auto take = [&](size_t bytes) {
    char* p = ws + o;
    o = (o + bytes + 255) & ~(size_t)255;
    return p;
  };
  int* flag    = (int*)take(4);
  int* srcs    = (int*)take((size_t)N_EDGES * 4);
  int* dstsb   = (int*)take((size_t)N_EDGES * 4);
  int* deg     = (int*)take((size_t)N_NODES * 4);
  int* roff    = (int*)take((size_t)(N_NODES + 1) * 4);
  int* cursor  = (int*)take((size_t)N_NODES * 4);
  int* adj     = (int*)take((size_t)N_EDGES * 4);
  float* dinv  = (float*)take((size_t)N_NODES * 4);
  float* als   = (float*)take((size_t)2 * N_NODES * 4);
  float* ald   = (float*)take((size_t)2 * N_NODES * 4);
  float* sc1   = (float*)take(128 * 4);
  float* sh1   = (float*)take(128 * 4);
  float* sc2   = (float*)take(128 * 4);
  float* sh2   = (float*)take(128 * 4);
  int* part    = (int*)take(256 * 4);
  unsigned short* Wt1  = (unsigned short*)take((size_t)128 * 128 * 2);
  unsigned short* WtG1 = (unsigned short*)take((size_t)256 * 128 * 2);
  unsigned short* Wt2  = (unsigned short*)take((size_t)128 * 128 * 2);
  unsigned short* WtG2 = (unsigned short*)take((size_t)128 * 128 * 2);
  unsigned short* Hb   = (unsigned short*)take((size_t)N_NODES * 256 * 2);
  float* bufF1 = (float*)take((size_t)N_NODES * 128 * 4);
  float* bufF2 = (float*)take((size_t)N_NODES * 128 * 4);
  (void)ws_size; (void)in_sizes; (void)n_in; (void)out_size;

  int eb = (N_EDGES + 255) / 256;
  int nb = (N_NODES + 255) / 256;
  int wb = (N_NODES + 3) / 4;        // wave per node, 4 waves/block
  int gb = (N_NODES + 63) / 64;      // 782 MFMA-GEMM blocks

  // edge dtype + CSR + folded affines + weight transposes (bf16)
  k_detect<<<1, 64, 0, stream>>>(eidx, flag);
  k_convert<<<eb, 256, 0, stream>>>(eidx, flag, srcs, dstsb);
  k_zero<<<nb, 256, 0, stream>>>(deg, N_NODES);
  k_count<<<eb, 256, 0, stream>>>(dstsb, deg);
  k_block_sums<<<nb, 256, 0, stream>>>(deg, part);
  k_scan_part<<<1, 256, 0, stream>>>(part, nb);
  k_scan_apply<<<nb, 256, 0, stream>>>(deg, part, roff, cursor, dinv);
  k_fill<<<eb, 256, 0, stream>>>(srcs, dstsb, cursor, adj);
  k_affine<<<1, 128, 0, stream>>>(b_gcn1, bn1_g, bn1_b, bn1_m, bn1_v, sc1, sh1);
  k_affine<<<1, 128, 0, stream>>>(b_gcn2, bn2_g, bn2_b, bn2_m, bn2_v, sc2, sh2);
  k_wt<<<64, 256, 0, stream>>>(W_gcn1, Wt1, 128, 7);
  k_wt<<<128, 256, 0, stream>>>(W_gat1, WtG1, 256, 8);
  k_wt<<<64, 256, 0, stream>>>(W_gcn2, Wt2, 128, 7);
  k_wt<<<64, 256, 0, stream>>>(W_gat2, WtG2, 128, 7);

  // Layer pipeline
  gemm_mfma<128><<<gb, 256, 0, stream>>>(x, Wt1, Hb, nullptr, nullptr, 0);
  gcn_pull<<<wb, 256, 0, stream>>>(Hb, adj, roff, dinv, bufF1);
  gemm_mfma<256><<<gb, 256, 0, stream>>>(bufF1, WtG1, Hb, sc1, sh1, 2);
  gat_al<128><<<wb, 256, 0, stream>>>(Hb, a_src1, a_dst1, als, ald);
  gat_pull<128><<<wb, 256, 0, stream>>>(Hb, adj, roff, als, ald, b_gat1, bufF1);
  gemm_mfma<128><<<gb, 256, 0, stream>>>(bufF1, Wt2, Hb, nullptr, nullptr, 1);
  gcn_pull<<<wb, 256, 0, stream>>>(Hb, adj, roff, dinv, bufF2);
  gemm_mfma<128><<<gb, 256, 0, stream>>>(bufF2, WtG2, Hb, sc2, sh2, 2);
  gat_al<64><<<wb, 256, 0, stream>>>(Hb, a_src2, a_dst2, als, ald);
  gat_pull<64><<<wb, 256, 0, stream>>>(Hb, adj, roff, als, ald, b_gat2, bufF1);
  log_softmax_k<<<wb, 256, 0, stream>>>(bufF1, (float*)d_out);
}